// Round 6
// baseline (494.745 us; speedup 1.0000x reference)
//
#include <hip/hip_runtime.h>

// ---------------------------------------------------------------------------
// Fused MHA block on MI355X (gfx950). fp16 MFMA 16x16x32, fp32 accum.
// Round-13:
//  * QKV GEMM: r11 EXACT (best measured: 118 us, 873 TF = m97-structure
//    ceiling). Five structural rewrites (r8-r12) all pinned at 33-36%
//    MfmaUtil -> stop churning QKV.
//  * flash_attn: T14 async-STAGE split. K/V staged via REGISTERS: issue
//    global_load_dwordx4(t+1) right after ds_write of tile t, so HBM latency
//    (~600-900cy) hides under compute(t) (~2500cy). Old path serialized
//    [sync -> global_load_lds -> sync+vmcnt(0)] per tile, exposing the full
//    load latency with only 2 blocks/CU to cover it. Exposed cost now just
//    8x ds_write_b128 (~100cy). LDS layout/swizzles/QK^T/softmax/PV
//    byte-identical. +32 VGPR (kreg/vreg), <=256/wave at 2 blocks/CU.
//  * wo GEMM (r7-verified 128x128) and cvt_all unchanged.
// ---------------------------------------------------------------------------

typedef _Float16 half8 __attribute__((ext_vector_type(8)));
typedef _Float16 half4 __attribute__((ext_vector_type(4)));
typedef float floatx4 __attribute__((ext_vector_type(4)));

__device__ __forceinline__ void async16(const void* g, void* l) {
  __builtin_amdgcn_global_load_lds((__attribute__((address_space(1))) void*)(g),
                                   (__attribute__((address_space(3))) void*)(l),
                                   16, 0, 0);
}

// ---- fp32 -> fp16 convert: x (2^21 quads) then 4 weights (2^20 each) -------
__global__ void cvt_all(const float* __restrict__ x, const float* __restrict__ w0,
                        const float* __restrict__ w1, const float* __restrict__ w2,
                        const float* __restrict__ w3, _Float16* __restrict__ xh,
                        _Float16* __restrict__ wh, float scale0) {
  int i = blockIdx.x * blockDim.x + threadIdx.x;
  const int XQ = 1 << 21;
  float sc = 1.0f;
  const float* src;
  _Float16* dst;
  int j;
  if (i < XQ) { src = x; dst = xh; j = i; }
  else {
    int t = i - XQ;
    int m = t >> 20;
    src = (m == 0) ? w0 : (m == 1) ? w1 : (m == 2) ? w2 : w3;
    if (m == 0) sc = scale0;
    dst = wh; j = t;
  }
  int js = (i < XQ) ? j : (j & ((1 << 20) - 1));
  float4 v = reinterpret_cast<const float4*>(src)[js];
  union { _Float16 h[4]; short4 s; } u;
  u.h[0] = (_Float16)(v.x * sc); u.h[1] = (_Float16)(v.y * sc);
  u.h[2] = (_Float16)(v.z * sc); u.h[3] = (_Float16)(v.w * sc);
  reinterpret_cast<short4*>(dst)[j] = u.s;
}

// ---- pipelined NT GEMM helpers ---------------------------------------------
__device__ __forceinline__ void rdA4(half8 (&f)[4][2], const _Float16* base,
                                     int ch0, int ch1) {
#pragma unroll
  for (int mt = 0; mt < 4; ++mt) {
    f[mt][0] = *reinterpret_cast<const half8*>(base + mt * 2048 + ch0);
    f[mt][1] = *reinterpret_cast<const half8*>(base + mt * 2048 + ch1);
  }
}
__device__ __forceinline__ void rdB2(half8 (&f)[2][2], const _Float16* base,
                                     int ch0, int ch1) {
#pragma unroll
  for (int nt = 0; nt < 2; ++nt) {
    f[nt][0] = *reinterpret_cast<const half8*>(base + nt * 4096 + ch0);
    f[nt][1] = *reinterpret_cast<const half8*>(base + nt * 4096 + ch1);
  }
}
template <int MO, int NO>
__device__ __forceinline__ void mmg16(floatx4 (&acc)[8][4], const half8 (&af)[4][2],
                                      const half8 (&bf)[2][2]) {
#pragma unroll
  for (int kk = 0; kk < 2; ++kk)
#pragma unroll
    for (int mt = 0; mt < 4; ++mt)
#pragma unroll
      for (int nt = 0; nt < 2; ++nt)
        acc[MO + mt][NO + nt] = __builtin_amdgcn_mfma_f32_16x16x32_f16(
            af[mt][kk], bf[nt][kk], acc[MO + mt][NO + nt], 0, 0, 0);
}

#define STAGE_AH0(buf, kk) { async16(ags + (kk), &(buf)[ldst]); \
                             async16(ags + 131072 + (kk), &(buf)[4096 + ldst]); }
#define STAGE_AH1(buf, kk) { async16(ags + 262144 + (kk), &(buf)[8192 + ldst]); \
                             async16(ags + 393216 + (kk), &(buf)[12288 + ldst]); }
#define STAGE_BH0(buf, kk) { async16(bgs + (kk), &(buf)[ldst]); \
                             async16(bgs + 131072 + (kk), &(buf)[4096 + ldst]); }
#define STAGE_BH1(buf, kk) { async16(bgs + 262144 + (kk), &(buf)[8192 + ldst]); \
                             async16(bgs + 393216 + (kk), &(buf)[12288 + ldst]); }
#define VMW(n) asm volatile("s_waitcnt vmcnt(" #n ")" ::: "memory")
#define SBAR() __builtin_amdgcn_s_barrier()
#define SCHED() __builtin_amdgcn_sched_barrier(0)
#define PRIO1() __builtin_amdgcn_s_setprio(1)
#define PRIO0() __builtin_amdgcn_s_setprio(0)

// ---- QKV NT GEMM (16x16x32): C[m][n] = sum_k A[m][k]*Bw[n][k] --------------
// 256x256 tile, 512 threads, 8 waves 2Mx4N, wave tile 128x64 (strided).
// r11 EXACT (118 us measured).
__global__ __launch_bounds__(512, 2)
void gemm_nt(const _Float16* __restrict__ A, const _Float16* __restrict__ Bw,
             void* __restrict__ Cv, void* __restrict__ Cv2) {
  __shared__ _Float16 As[2][256 * 64];
  __shared__ _Float16 Bs[2][256 * 64];
  const int tid = threadIdx.x;
  const int wave = tid >> 6, lane = tid & 63;
  const int wm = wave >> 2, wn = wave & 3;      // 2M x 4N wave grid
  const int l15 = lane & 15, l4 = lane >> 4;

  // XCD swizzle, bn-fastest chunks (A stays L2-resident per XCD).
  const int NBN = 24;
  const int nwg = NBN * 16;                     // 384, %8 == 0
  const int swz = (blockIdx.x & 7) * (nwg >> 3) + (blockIdx.x >> 3);
  const int bn = swz % NBN, bm = swz / NBN;

  // Staging: xor-swizzled global source, linear LDS dest. Round j = 64 rows.
  const int srow = tid >> 3;
  const int g = (tid & 7) ^ (srow & 7);
  const _Float16* ags = A + (size_t)(bm * 256 + srow) * 2048 + g * 8;
  const _Float16* bgs = Bw + (size_t)(bn * 256 + srow) * 2048 + g * 8;
  const int ldst = tid * 8;

  // Fragment coords. A row = mt*32 + wm*16 + l15; B row = nt*64 + wn*16 + l15.
  const int arow = wm * 16 + l15;
  const int brow = wn * 16 + l15;
  const int ch0 = (l4 ^ (l15 & 7)) * 8;
  const int ch1 = ((l4 + 4) ^ (l15 & 7)) * 8;

  // Prologue: stage t0 fully + A-h0/B-h0 of t1 (the "p2/p3 of t=-1" stages).
  STAGE_AH0(As[0], 0); STAGE_BH0(Bs[0], 0);
  STAGE_BH1(Bs[0], 0); STAGE_AH1(As[0], 0);
  STAGE_AH0(As[1], 64); STAGE_BH0(Bs[1], 64);
  VMW(4);                                       // retire the 8 t0 loads
  SBAR();

  floatx4 acc[8][4] = {};
  half8 afA[4][2], afB[4][2], bfA[2][2], bfB[2][2];
  rdA4(afA, &As[0][arow * 64], ch0, ch1);       // pre-read t0 Q00 operands
  rdB2(bfA, &Bs[0][brow * 64], ch0, ch1);

#pragma unroll 2
  for (int t = 0; t < 30; ++t) {
    const int c = t & 1, nx = c ^ 1;
    const int k1 = t * 64 + 64, k2 = t * 64 + 128;
    const _Float16* Ac = &As[c][0];
    const _Float16* Bc = &Bs[c][0];

    // p0: MFMA Q00(t); read bfB(t); stage B-h1(t+1)
    PRIO1(); mmg16<0, 0>(acc, afA, bfA); PRIO0();
    rdB2(bfB, Bc + brow * 64 + 8192, ch0, ch1);
    STAGE_BH1(Bs[nx], k1);
    SCHED(); VMW(6); SBAR();

    // p1: MFMA Q01(t); read afB(t); stage A-h1(t+1)
    PRIO1(); mmg16<0, 2>(acc, afA, bfB); PRIO0();
    rdA4(afB, Ac + arow * 64 + 8192, ch0, ch1);
    STAGE_AH1(As[nx], k1);
    SCHED(); VMW(6); SBAR();

    // p2: MFMA Q10(t); stage A-h0(t+2) into CURRENT buffer (reads done @p0)
    PRIO1(); mmg16<4, 0>(acc, afB, bfA); PRIO0();
    STAGE_AH0(As[c], k2);
    SCHED(); VMW(6); SBAR();

    // p3: MFMA Q11(t); read afA/bfA(t+1); stage B-h0(t+2) into CURRENT buffer
    PRIO1(); mmg16<4, 2>(acc, afB, bfB); PRIO0();
    rdA4(afA, &As[nx][arow * 64], ch0, ch1);
    rdB2(bfA, &Bs[nx][brow * 64], ch0, ch1);
    STAGE_BH0(Bs[c], k2);
    SCHED(); VMW(6); SBAR();
  }

  // ---- peeled t=30 (cur=buf0): stage only t31's remaining halves ----
  {
    const _Float16* Ac = &As[0][0];
    const _Float16* Bc = &Bs[0][0];
    PRIO1(); mmg16<0, 0>(acc, afA, bfA); PRIO0();
    rdB2(bfB, Bc + brow * 64 + 8192, ch0, ch1);
    STAGE_BH1(Bs[1], 1984);
    SCHED(); VMW(6); SBAR();

    PRIO1(); mmg16<0, 2>(acc, afA, bfB); PRIO0();
    rdA4(afB, Ac + arow * 64 + 8192, ch0, ch1);
    STAGE_AH1(As[1], 1984);
    SCHED(); VMW(6); SBAR();

    PRIO1(); mmg16<4, 0>(acc, afB, bfA); PRIO0();
    SCHED(); VMW(4); SBAR();                   // retire B-h0(31)

    PRIO1(); mmg16<4, 2>(acc, afB, bfB); PRIO0();
    rdA4(afA, &As[1][arow * 64], ch0, ch1);
    rdB2(bfA, &Bs[1][brow * 64], ch0, ch1);
    SCHED(); VMW(2); SBAR();                   // retire B-h1(31)
  }
  // ---- peeled t=31 (cur=buf1): no staging ----
  {
    const _Float16* Ac = &As[1][0];
    const _Float16* Bc = &Bs[1][0];
    PRIO1(); mmg16<0, 0>(acc, afA, bfA); PRIO0();
    rdB2(bfB, Bc + brow * 64 + 8192, ch0, ch1);
    SCHED(); VMW(0); SBAR();                   // retire A-h1(31)
    PRIO1(); mmg16<0, 2>(acc, afA, bfB); PRIO0();
    rdA4(afB, Ac + arow * 64 + 8192, ch0, ch1);
    mmg16<4, 0>(acc, afB, bfA);
    mmg16<4, 2>(acc, afB, bfB);
  }

  // ---- fused QKV epilogue (row = bm*256 + mt*32 + wm*16 + l4*4 + r,
  //                          col = bn*256 + nt*64 + wn*16 + l15) ----
  const int cb0 = bn * 256;
  if (cb0 < 4096) {             // Q or K: row-major fp16, ld 2048
    _Float16* C = (_Float16*)Cv + (size_t)(cb0 >> 11) * (4096ull * 2048);
#pragma unroll
    for (int mt = 0; mt < 8; ++mt)
#pragma unroll
      for (int nt = 0; nt < 4; ++nt) {
        int r0 = bm * 256 + mt * 32 + wm * 16 + l4 * 4;
        int cg = (cb0 + nt * 64 + wn * 16 + l15) & 2047;
#pragma unroll
        for (int r = 0; r < 4; ++r)
          C[(size_t)(r0 + r) * 2048 + cg] = (_Float16)acc[mt][nt][r];
      }
  } else {                      // V: per-batch transposed [b][d][s]
    _Float16* C = (_Float16*)Cv2;
#pragma unroll
    for (int mt = 0; mt < 8; ++mt)
#pragma unroll
      for (int nt = 0; nt < 4; ++nt) {
        int m0 = bm * 256 + mt * 32 + wm * 16 + l4 * 4;
        int d = cb0 + nt * 64 + wn * 16 + l15 - 4096;
        size_t base = (size_t)(m0 >> 11) * (2048ull * 2048) + (size_t)d * 2048 + (m0 & 2047);
        union { _Float16 h[4]; short4 s; } u;
#pragma unroll
        for (int r = 0; r < 4; ++r) u.h[r] = (_Float16)acc[mt][nt][r];
        *reinterpret_cast<short4*>(C + base) = u.s;
      }
  }
}

// ---- wo GEMM: r7-verified 128x128 2-phase NT GEMM, fp32 out ----------------
__global__ __launch_bounds__(256)
void gemm_wo(const _Float16* __restrict__ A, const _Float16* __restrict__ Bw,
             float* __restrict__ C) {
  __shared__ _Float16 As[128 * 64];
  __shared__ _Float16 Bs[128 * 64];
  const int tid = threadIdx.x;
  const int wave = tid >> 6, lane = tid & 63;
  const int wm = wave >> 1, wn = wave & 1;
  const int l15 = lane & 15, l4 = lane >> 4;
  const int bm = blockIdx.y, bn = blockIdx.x;

  floatx4 acc[4][4] = {};

  for (int k0 = 0; k0 < 2048; k0 += 64) {
    __syncthreads();
#pragma unroll
    for (int i = 0; i < 4; ++i) {
      int c = i * 256 + tid;
      int row = c >> 3, cc = c & 7;
      int gg = cc ^ (row & 7);
      async16(A + (size_t)(bm * 128 + row) * 2048 + k0 + gg * 8, &As[c * 8]);
      async16(Bw + (size_t)(bn * 128 + row) * 2048 + k0 + gg * 8, &Bs[c * 8]);
    }
    __syncthreads();
#pragma unroll
    for (int ks = 0; ks < 2; ++ks) {
      half8 af[4], bf[4];
      int ch = (ks * 4 + l4) ^ (l15 & 7);
#pragma unroll
      for (int t = 0; t < 4; ++t) {
        af[t] = *reinterpret_cast<const half8*>(&As[(wm * 64 + t * 16 + l15) * 64 + ch * 8]);
        bf[t] = *reinterpret_cast<const half8*>(&Bs[(wn * 64 + t * 16 + l15) * 64 + ch * 8]);
      }
#pragma unroll
      for (int mt = 0; mt < 4; ++mt)
#pragma unroll
        for (int nt = 0; nt < 4; ++nt)
          acc[mt][nt] = __builtin_amdgcn_mfma_f32_16x16x32_f16(af[mt], bf[nt], acc[mt][nt], 0, 0, 0);
    }
  }

  const int rbase = bm * 128 + wm * 64;
  const int cbase = bn * 128 + wn * 64;
#pragma unroll
  for (int mt = 0; mt < 4; ++mt)
#pragma unroll
    for (int nt = 0; nt < 4; ++nt) {
      int r0 = rbase + mt * 16 + l4 * 4;
      int cg = cbase + nt * 16 + l15;
#pragma unroll
      for (int r = 0; r < 4; ++r)
        C[(size_t)(r0 + r) * 2048 + cg] = acc[mt][nt][r];
    }
}

// ---- Flash attention (T14 async-STAGE: reg-staged K/V, single-buffer LDS) --
// grid = (16 q-tiles of 128, 32 b*h); block = 256 (4 waves x 32 q rows).
__global__ __launch_bounds__(256, 2)
void flash_attn(const _Float16* __restrict__ Q, const _Float16* __restrict__ Kg,
                const _Float16* __restrict__ Vt, _Float16* __restrict__ O) {
  __shared__ _Float16 Ks[64 * 128];   // [key][hd], 16-chunk xor swizzle
  __shared__ _Float16 Vs[128 * 64];   // [d][s],    8-chunk xor swizzle
  __shared__ _Float16 Ps[128 * 64];   // [q][key],  8-chunk xor swizzle
  const int tid = threadIdx.x, wave = tid >> 6, lane = tid & 63;
  const int l15 = lane & 15, l4 = lane >> 4;
  const int bh = blockIdx.y, b = bh >> 4, h = bh & 15;
  const int q0 = blockIdx.x * 128;

  const _Float16* Qp = Q + ((size_t)(b * 2048 + q0 + wave * 32)) * 2048 + h * 128;
  const _Float16* Kp = Kg + (size_t)b * 2048 * 2048 + h * 128;
  const _Float16* Vp = Vt + (size_t)b * 2048 * 2048 + (size_t)(h * 128) * 2048;

  // Per-thread staging coords (same layout/swizzle as the async16 version:
  // linear LDS dest c*8, xor-swizzled global source).
  const _Float16* ka[4]; const _Float16* va[4];
  int kl[4], vl[4];
#pragma unroll
  for (int i = 0; i < 4; ++i) {
    int c = i * 256 + tid;
    int row = c >> 4, cc = c & 15, gk = cc ^ (row & 15);
    ka[i] = Kp + (size_t)row * 2048 + gk * 8;   // + k0*2048 per tile
    kl[i] = c * 8;
    int rv = c >> 3, cv = c & 7, gv = cv ^ (rv & 7);
    va[i] = Vp + (size_t)rv * 2048 + gv * 8;    // + k0 per tile
    vl[i] = c * 8;
  }

  // Issue tile-0 loads first (HBM latency overlaps Q-load + setup).
  int4 kreg[4], vreg[4];
#pragma unroll
  for (int i = 0; i < 4; ++i) kreg[i] = *reinterpret_cast<const int4*>(ka[i]);
#pragma unroll
  for (int i = 0; i < 4; ++i) vreg[i] = *reinterpret_cast<const int4*>(va[i]);

  half8 qf[2][4];
#pragma unroll
  for (int qt = 0; qt < 2; ++qt)
#pragma unroll
    for (int ks = 0; ks < 4; ++ks)
      qf[qt][ks] = *reinterpret_cast<const half8*>(
          Qp + (size_t)(qt * 16 + l15) * 2048 + ks * 32 + l4 * 8);

  floatx4 oacc[2][8] = {};
  float lsumq[2] = {0.f, 0.f};        // per-lane: sum over its s for q = lane&15

  for (int t = 0; t < 32; ++t) {
    __syncthreads();                  // all waves done reading tile t-1
#pragma unroll
    for (int i = 0; i < 4; ++i) *reinterpret_cast<int4*>(&Ks[kl[i]]) = kreg[i];
#pragma unroll
    for (int i = 0; i < 4; ++i) *reinterpret_cast<int4*>(&Vs[vl[i]]) = vreg[i];
    if (t < 31) {                     // issue t+1 loads; land during compute(t)
      const int kn = t * 64 + 64;
#pragma unroll
      for (int i = 0; i < 4; ++i)
        kreg[i] = *reinterpret_cast<const int4*>(ka[i] + (size_t)kn * 2048);
#pragma unroll
      for (int i = 0; i < 4; ++i)
        vreg[i] = *reinterpret_cast<const int4*>(va[i] + kn);
    }
    __syncthreads();                  // tile t visible to all waves

    // ---- S^T = K Q^T : sacc[st][qt], col=q, row=s ----
    floatx4 sacc[4][2] = {};
#pragma unroll
    for (int ks = 0; ks < 4; ++ks) {
      half8 kf[4];
#pragma unroll
      for (int st = 0; st < 4; ++st) {
        int row = st * 16 + l15;
        int ch = (ks * 4 + l4) ^ l15;             // row & 15 == l15
        kf[st] = *reinterpret_cast<const half8*>(&Ks[row * 128 + ch * 8]);
      }
#pragma unroll
      for (int st = 0; st < 4; ++st)
#pragma unroll
        for (int qt = 0; qt < 2; ++qt)
          sacc[st][qt] = __builtin_amdgcn_mfma_f32_16x16x32_f16(kf[st], qf[qt][ks], sacc[st][qt], 0, 0, 0);
    }

    // ---- p = 2^s; packed b64 Ps write (4 consecutive s per lane) ----
#pragma unroll
    for (int qt = 0; qt < 2; ++qt)
#pragma unroll
      for (int st = 0; st < 4; ++st) {
        float p0 = exp2f(sacc[st][qt][0]);
        float p1 = exp2f(sacc[st][qt][1]);
        float p2 = exp2f(sacc[st][qt][2]);
        float p3 = exp2f(sacc[st][qt][3]);
        lsumq[qt] += (p0 + p1) + (p2 + p3);
        half4 pv;
        pv[0] = (_Float16)p0; pv[1] = (_Float16)p1;
        pv[2] = (_Float16)p2; pv[3] = (_Float16)p3;
        int ch = (st * 2 + (l4 >> 1)) ^ (l15 & 7);
        *reinterpret_cast<half4*>(
            &Ps[(wave * 32 + qt * 16 + l15) * 64 + ch * 8 + (l4 & 1) * 4]) = pv;
      }

    __builtin_amdgcn_s_waitcnt(0xC07F);  // lgkmcnt(0): own-wave ds_write->ds_read

    // ---- O += P V  (V stored (d,s): NT GEMM) ----
#pragma unroll
    for (int ks2 = 0; ks2 < 2; ++ks2) {
      half8 pf[2];
#pragma unroll
      for (int mt = 0; mt < 2; ++mt)
        pf[mt] = *reinterpret_cast<const half8*>(
            &Ps[(wave * 32 + mt * 16 + l15) * 64 + (((ks2 * 4 + l4) ^ (l15 & 7)) * 8)]);
#pragma unroll
      for (int nt2 = 0; nt2 < 8; ++nt2) {
        int row = nt2 * 16 + l15;
        int ch = (ks2 * 4 + l4) ^ (row & 7);
        half8 vf = *reinterpret_cast<const half8*>(&Vs[row * 64 + ch * 8]);
#pragma unroll
        for (int mt = 0; mt < 2; ++mt)
          oacc[mt][nt2] = __builtin_amdgcn_mfma_f32_16x16x32_f16(pf[mt], vf, oacc[mt][nt2], 0, 0, 0);
      }
    }
  }

#pragma unroll
  for (int qt = 0; qt < 2; ++qt) {
    lsumq[qt] += __shfl_xor(lsumq[qt], 16);
    lsumq[qt] += __shfl_xor(lsumq[qt], 32);
  }

  _Float16* Op = O + ((size_t)(b * 2048 + q0 + wave * 32)) * 2048 + h * 128;
#pragma unroll
  for (int mt = 0; mt < 2; ++mt)
#pragma unroll
    for (int r = 0; r < 4; ++r) {
      float inv = 1.0f / __shfl(lsumq[mt], l4 * 4 + r);
#pragma unroll
      for (int nt2 = 0; nt2 < 8; ++nt2) {
        int row = mt * 16 + l4 * 4 + r;
        int col = nt2 * 16 + l15;
        Op[(size_t)row * 2048 + col] = (_Float16)(oacc[mt][nt2][r] * inv);
      }
    }
}

// ---------------------------------------------------------------------------
extern "C" void kernel_launch(void* const* d_in, const int* in_sizes, int n_in,
                              void* d_out, int out_size, void* d_ws, size_t ws_size,
                              hipStream_t stream) {
  const float* x = (const float*)d_in[0];
  const float* wq = (const float*)d_in[1];
  const float* wk = (const float*)d_in[2];
  const float* wv = (const float*)d_in[3];
  const float* wo = (const float*)d_in[4];
  float* out = (float*)d_out;

  const size_t XN = (size_t)4096 * 2048;
  const size_t WN = (size_t)2048 * 2048;
  _Float16* xh = (_Float16*)d_ws;
  _Float16* qh = xh + XN;          // Q then K contiguous (row-major, ld 2048)
  _Float16* vth = xh + 3 * XN;     // per-batch transposed V
  _Float16* oh = xh + 4 * XN;
  _Float16* wqh = xh + 5 * XN;     // wq,wk,wv,wo contiguous

  const float SM_SCALE = 0.08838834764831845f * 1.4426950408889634f;

  cvt_all<<<dim3(24576), 256, 0, stream>>>(x, wq, wk, wv, wo, xh, wqh, SM_SCALE);
  gemm_nt<<<dim3(384), 512, 0, stream>>>(xh, wqh, qh, vth);
  flash_attn<<<dim3(16, 32), 256, 0, stream>>>(qh, qh + XN, vth, oh);
  gemm_wo<<<dim3(16, 32), 256, 0, stream>>>(oh, wqh + 3 * WN, out);
}

// Round 7
// 372.649 us; speedup vs baseline: 1.3276x; 1.3276x over previous
//
#include <hip/hip_runtime.h>

// ---------------------------------------------------------------------------
// Fused MHA block on MI355X (gfx950). fp16 MFMA 16x16x32, fp32 accum.
// Round-14:
//  * flash_attn: r13's reg-staged K/V REVERTED (counters: 341MB scratch
//    writes + 2^21 bank conflicts -> 202us, HBM-bound on spills). Back to
//    global_load_lds, but now DOUBLE-BUFFERED (K/V 2x -> LDS 80KB, still
//    exactly 2 blocks/CU of 160KB): issue tile t+1's 8 gload_lds BEFORE
//    compute(t), vmcnt(0) AFTER compute(t) -> the wait has a full compute
//    phase (~2500cy) of slack instead of r7's zero-slack issue->drain.
//    One barrier/tile; buf[nx] written only after the barrier ending all
//    reads of it (race-checked); uniform barrier count (no divergence).
//  * QKV GEMM: r11 exact (118us measured, best of 6 attempts).
//  * wo GEMM (r7-verified 128x128) and cvt_all unchanged.
// ---------------------------------------------------------------------------

typedef _Float16 half8 __attribute__((ext_vector_type(8)));
typedef _Float16 half4 __attribute__((ext_vector_type(4)));
typedef float floatx4 __attribute__((ext_vector_type(4)));

__device__ __forceinline__ void async16(const void* g, void* l) {
  __builtin_amdgcn_global_load_lds((__attribute__((address_space(1))) void*)(g),
                                   (__attribute__((address_space(3))) void*)(l),
                                   16, 0, 0);
}

// ---- fp32 -> fp16 convert: x (2^21 quads) then 4 weights (2^20 each) -------
__global__ void cvt_all(const float* __restrict__ x, const float* __restrict__ w0,
                        const float* __restrict__ w1, const float* __restrict__ w2,
                        const float* __restrict__ w3, _Float16* __restrict__ xh,
                        _Float16* __restrict__ wh, float scale0) {
  int i = blockIdx.x * blockDim.x + threadIdx.x;
  const int XQ = 1 << 21;
  float sc = 1.0f;
  const float* src;
  _Float16* dst;
  int j;
  if (i < XQ) { src = x; dst = xh; j = i; }
  else {
    int t = i - XQ;
    int m = t >> 20;
    src = (m == 0) ? w0 : (m == 1) ? w1 : (m == 2) ? w2 : w3;
    if (m == 0) sc = scale0;
    dst = wh; j = t;
  }
  int js = (i < XQ) ? j : (j & ((1 << 20) - 1));
  float4 v = reinterpret_cast<const float4*>(src)[js];
  union { _Float16 h[4]; short4 s; } u;
  u.h[0] = (_Float16)(v.x * sc); u.h[1] = (_Float16)(v.y * sc);
  u.h[2] = (_Float16)(v.z * sc); u.h[3] = (_Float16)(v.w * sc);
  reinterpret_cast<short4*>(dst)[j] = u.s;
}

// ---- pipelined NT GEMM helpers ---------------------------------------------
__device__ __forceinline__ void rdA4(half8 (&f)[4][2], const _Float16* base,
                                     int ch0, int ch1) {
#pragma unroll
  for (int mt = 0; mt < 4; ++mt) {
    f[mt][0] = *reinterpret_cast<const half8*>(base + mt * 2048 + ch0);
    f[mt][1] = *reinterpret_cast<const half8*>(base + mt * 2048 + ch1);
  }
}
__device__ __forceinline__ void rdB2(half8 (&f)[2][2], const _Float16* base,
                                     int ch0, int ch1) {
#pragma unroll
  for (int nt = 0; nt < 2; ++nt) {
    f[nt][0] = *reinterpret_cast<const half8*>(base + nt * 4096 + ch0);
    f[nt][1] = *reinterpret_cast<const half8*>(base + nt * 4096 + ch1);
  }
}
template <int MO, int NO>
__device__ __forceinline__ void mmg16(floatx4 (&acc)[8][4], const half8 (&af)[4][2],
                                      const half8 (&bf)[2][2]) {
#pragma unroll
  for (int kk = 0; kk < 2; ++kk)
#pragma unroll
    for (int mt = 0; mt < 4; ++mt)
#pragma unroll
      for (int nt = 0; nt < 2; ++nt)
        acc[MO + mt][NO + nt] = __builtin_amdgcn_mfma_f32_16x16x32_f16(
            af[mt][kk], bf[nt][kk], acc[MO + mt][NO + nt], 0, 0, 0);
}

#define STAGE_AH0(buf, kk) { async16(ags + (kk), &(buf)[ldst]); \
                             async16(ags + 131072 + (kk), &(buf)[4096 + ldst]); }
#define STAGE_AH1(buf, kk) { async16(ags + 262144 + (kk), &(buf)[8192 + ldst]); \
                             async16(ags + 393216 + (kk), &(buf)[12288 + ldst]); }
#define STAGE_BH0(buf, kk) { async16(bgs + (kk), &(buf)[ldst]); \
                             async16(bgs + 131072 + (kk), &(buf)[4096 + ldst]); }
#define STAGE_BH1(buf, kk) { async16(bgs + 262144 + (kk), &(buf)[8192 + ldst]); \
                             async16(bgs + 393216 + (kk), &(buf)[12288 + ldst]); }
#define VMW(n) asm volatile("s_waitcnt vmcnt(" #n ")" ::: "memory")
#define SBAR() __builtin_amdgcn_s_barrier()
#define SCHED() __builtin_amdgcn_sched_barrier(0)
#define PRIO1() __builtin_amdgcn_s_setprio(1)
#define PRIO0() __builtin_amdgcn_s_setprio(0)

// ---- QKV NT GEMM (16x16x32): C[m][n] = sum_k A[m][k]*Bw[n][k] --------------
// 256x256 tile, 512 threads, 8 waves 2Mx4N, wave tile 128x64 (strided).
// r11 EXACT (118 us measured).
__global__ __launch_bounds__(512, 2)
void gemm_nt(const _Float16* __restrict__ A, const _Float16* __restrict__ Bw,
             void* __restrict__ Cv, void* __restrict__ Cv2) {
  __shared__ _Float16 As[2][256 * 64];
  __shared__ _Float16 Bs[2][256 * 64];
  const int tid = threadIdx.x;
  const int wave = tid >> 6, lane = tid & 63;
  const int wm = wave >> 2, wn = wave & 3;      // 2M x 4N wave grid
  const int l15 = lane & 15, l4 = lane >> 4;

  // XCD swizzle, bn-fastest chunks (A stays L2-resident per XCD).
  const int NBN = 24;
  const int nwg = NBN * 16;                     // 384, %8 == 0
  const int swz = (blockIdx.x & 7) * (nwg >> 3) + (blockIdx.x >> 3);
  const int bn = swz % NBN, bm = swz / NBN;

  // Staging: xor-swizzled global source, linear LDS dest. Round j = 64 rows.
  const int srow = tid >> 3;
  const int g = (tid & 7) ^ (srow & 7);
  const _Float16* ags = A + (size_t)(bm * 256 + srow) * 2048 + g * 8;
  const _Float16* bgs = Bw + (size_t)(bn * 256 + srow) * 2048 + g * 8;
  const int ldst = tid * 8;

  // Fragment coords. A row = mt*32 + wm*16 + l15; B row = nt*64 + wn*16 + l15.
  const int arow = wm * 16 + l15;
  const int brow = wn * 16 + l15;
  const int ch0 = (l4 ^ (l15 & 7)) * 8;
  const int ch1 = ((l4 + 4) ^ (l15 & 7)) * 8;

  // Prologue: stage t0 fully + A-h0/B-h0 of t1 (the "p2/p3 of t=-1" stages).
  STAGE_AH0(As[0], 0); STAGE_BH0(Bs[0], 0);
  STAGE_BH1(Bs[0], 0); STAGE_AH1(As[0], 0);
  STAGE_AH0(As[1], 64); STAGE_BH0(Bs[1], 64);
  VMW(4);                                       // retire the 8 t0 loads
  SBAR();

  floatx4 acc[8][4] = {};
  half8 afA[4][2], afB[4][2], bfA[2][2], bfB[2][2];
  rdA4(afA, &As[0][arow * 64], ch0, ch1);       // pre-read t0 Q00 operands
  rdB2(bfA, &Bs[0][brow * 64], ch0, ch1);

#pragma unroll 2
  for (int t = 0; t < 30; ++t) {
    const int c = t & 1, nx = c ^ 1;
    const int k1 = t * 64 + 64, k2 = t * 64 + 128;
    const _Float16* Ac = &As[c][0];
    const _Float16* Bc = &Bs[c][0];

    // p0: MFMA Q00(t); read bfB(t); stage B-h1(t+1)
    PRIO1(); mmg16<0, 0>(acc, afA, bfA); PRIO0();
    rdB2(bfB, Bc + brow * 64 + 8192, ch0, ch1);
    STAGE_BH1(Bs[nx], k1);
    SCHED(); VMW(6); SBAR();

    // p1: MFMA Q01(t); read afB(t); stage A-h1(t+1)
    PRIO1(); mmg16<0, 2>(acc, afA, bfB); PRIO0();
    rdA4(afB, Ac + arow * 64 + 8192, ch0, ch1);
    STAGE_AH1(As[nx], k1);
    SCHED(); VMW(6); SBAR();

    // p2: MFMA Q10(t); stage A-h0(t+2) into CURRENT buffer (reads done @p0)
    PRIO1(); mmg16<4, 0>(acc, afB, bfA); PRIO0();
    STAGE_AH0(As[c], k2);
    SCHED(); VMW(6); SBAR();

    // p3: MFMA Q11(t); read afA/bfA(t+1); stage B-h0(t+2) into CURRENT buffer
    PRIO1(); mmg16<4, 2>(acc, afB, bfB); PRIO0();
    rdA4(afA, &As[nx][arow * 64], ch0, ch1);
    rdB2(bfA, &Bs[nx][brow * 64], ch0, ch1);
    STAGE_BH0(Bs[c], k2);
    SCHED(); VMW(6); SBAR();
  }

  // ---- peeled t=30 (cur=buf0): stage only t31's remaining halves ----
  {
    const _Float16* Ac = &As[0][0];
    const _Float16* Bc = &Bs[0][0];
    PRIO1(); mmg16<0, 0>(acc, afA, bfA); PRIO0();
    rdB2(bfB, Bc + brow * 64 + 8192, ch0, ch1);
    STAGE_BH1(Bs[1], 1984);
    SCHED(); VMW(6); SBAR();

    PRIO1(); mmg16<0, 2>(acc, afA, bfB); PRIO0();
    rdA4(afB, Ac + arow * 64 + 8192, ch0, ch1);
    STAGE_AH1(As[1], 1984);
    SCHED(); VMW(6); SBAR();

    PRIO1(); mmg16<4, 0>(acc, afB, bfA); PRIO0();
    SCHED(); VMW(4); SBAR();                   // retire B-h0(31)

    PRIO1(); mmg16<4, 2>(acc, afB, bfB); PRIO0();
    rdA4(afA, &As[1][arow * 64], ch0, ch1);
    rdB2(bfA, &Bs[1][brow * 64], ch0, ch1);
    SCHED(); VMW(2); SBAR();                   // retire B-h1(31)
  }
  // ---- peeled t=31 (cur=buf1): no staging ----
  {
    const _Float16* Ac = &As[1][0];
    const _Float16* Bc = &Bs[1][0];
    PRIO1(); mmg16<0, 0>(acc, afA, bfA); PRIO0();
    rdB2(bfB, Bc + brow * 64 + 8192, ch0, ch1);
    SCHED(); VMW(0); SBAR();                   // retire A-h1(31)
    PRIO1(); mmg16<0, 2>(acc, afA, bfB); PRIO0();
    rdA4(afB, Ac + arow * 64 + 8192, ch0, ch1);
    mmg16<4, 0>(acc, afB, bfA);
    mmg16<4, 2>(acc, afB, bfB);
  }

  // ---- fused QKV epilogue (row = bm*256 + mt*32 + wm*16 + l4*4 + r,
  //                          col = bn*256 + nt*64 + wn*16 + l15) ----
  const int cb0 = bn * 256;
  if (cb0 < 4096) {             // Q or K: row-major fp16, ld 2048
    _Float16* C = (_Float16*)Cv + (size_t)(cb0 >> 11) * (4096ull * 2048);
#pragma unroll
    for (int mt = 0; mt < 8; ++mt)
#pragma unroll
      for (int nt = 0; nt < 4; ++nt) {
        int r0 = bm * 256 + mt * 32 + wm * 16 + l4 * 4;
        int cg = (cb0 + nt * 64 + wn * 16 + l15) & 2047;
#pragma unroll
        for (int r = 0; r < 4; ++r)
          C[(size_t)(r0 + r) * 2048 + cg] = (_Float16)acc[mt][nt][r];
      }
  } else {                      // V: per-batch transposed [b][d][s]
    _Float16* C = (_Float16*)Cv2;
#pragma unroll
    for (int mt = 0; mt < 8; ++mt)
#pragma unroll
      for (int nt = 0; nt < 4; ++nt) {
        int m0 = bm * 256 + mt * 32 + wm * 16 + l4 * 4;
        int d = cb0 + nt * 64 + wn * 16 + l15 - 4096;
        size_t base = (size_t)(m0 >> 11) * (2048ull * 2048) + (size_t)d * 2048 + (m0 & 2047);
        union { _Float16 h[4]; short4 s; } u;
#pragma unroll
        for (int r = 0; r < 4; ++r) u.h[r] = (_Float16)acc[mt][nt][r];
        *reinterpret_cast<short4*>(C + base) = u.s;
      }
  }
}

// ---- wo GEMM: r7-verified 128x128 2-phase NT GEMM, fp32 out ----------------
__global__ __launch_bounds__(256)
void gemm_wo(const _Float16* __restrict__ A, const _Float16* __restrict__ Bw,
             float* __restrict__ C) {
  __shared__ _Float16 As[128 * 64];
  __shared__ _Float16 Bs[128 * 64];
  const int tid = threadIdx.x;
  const int wave = tid >> 6, lane = tid & 63;
  const int wm = wave >> 1, wn = wave & 1;
  const int l15 = lane & 15, l4 = lane >> 4;
  const int bm = blockIdx.y, bn = blockIdx.x;

  floatx4 acc[4][4] = {};

  for (int k0 = 0; k0 < 2048; k0 += 64) {
    __syncthreads();
#pragma unroll
    for (int i = 0; i < 4; ++i) {
      int c = i * 256 + tid;
      int row = c >> 3, cc = c & 7;
      int gg = cc ^ (row & 7);
      async16(A + (size_t)(bm * 128 + row) * 2048 + k0 + gg * 8, &As[c * 8]);
      async16(Bw + (size_t)(bn * 128 + row) * 2048 + k0 + gg * 8, &Bs[c * 8]);
    }
    __syncthreads();
#pragma unroll
    for (int ks = 0; ks < 2; ++ks) {
      half8 af[4], bf[4];
      int ch = (ks * 4 + l4) ^ (l15 & 7);
#pragma unroll
      for (int t = 0; t < 4; ++t) {
        af[t] = *reinterpret_cast<const half8*>(&As[(wm * 64 + t * 16 + l15) * 64 + ch * 8]);
        bf[t] = *reinterpret_cast<const half8*>(&Bs[(wn * 64 + t * 16 + l15) * 64 + ch * 8]);
      }
#pragma unroll
      for (int mt = 0; mt < 4; ++mt)
#pragma unroll
        for (int nt = 0; nt < 4; ++nt)
          acc[mt][nt] = __builtin_amdgcn_mfma_f32_16x16x32_f16(af[mt], bf[nt], acc[mt][nt], 0, 0, 0);
    }
  }

  const int rbase = bm * 128 + wm * 64;
  const int cbase = bn * 128 + wn * 64;
#pragma unroll
  for (int mt = 0; mt < 4; ++mt)
#pragma unroll
    for (int nt = 0; nt < 4; ++nt) {
      int r0 = rbase + mt * 16 + l4 * 4;
      int cg = cbase + nt * 16 + l15;
#pragma unroll
      for (int r = 0; r < 4; ++r)
        C[(size_t)(r0 + r) * 2048 + cg] = acc[mt][nt][r];
    }
}

// ---- Flash attention: double-buffered global_load_lds pipeline -------------
// grid = (16 q-tiles of 128, 32 b*h); block = 256 (4 waves x 32 q rows).
// LDS 80 KB (K/V double-buffered + Ps) -> exactly 2 blocks/CU of 160 KB.
__global__ __launch_bounds__(256, 2)
void flash_attn(const _Float16* __restrict__ Q, const _Float16* __restrict__ Kg,
                const _Float16* __restrict__ Vt, _Float16* __restrict__ O) {
  __shared__ _Float16 Ks[2][64 * 128];  // [key][hd], 16-chunk xor swizzle
  __shared__ _Float16 Vs[2][128 * 64];  // [d][s],    8-chunk xor swizzle
  __shared__ _Float16 Ps[128 * 64];     // [q][key],  8-chunk xor swizzle
  const int tid = threadIdx.x, wave = tid >> 6, lane = tid & 63;
  const int l15 = lane & 15, l4 = lane >> 4;
  const int bh = blockIdx.y, b = bh >> 4, h = bh & 15;
  const int q0 = blockIdx.x * 128;

  const _Float16* Qp = Q + ((size_t)(b * 2048 + q0 + wave * 32)) * 2048 + h * 128;
  const _Float16* Kp = Kg + (size_t)b * 2048 * 2048 + h * 128;
  const _Float16* Vp = Vt + (size_t)b * 2048 * 2048 + (size_t)(h * 128) * 2048;

  // Per-thread staging coords (identical layout/swizzle to r7).
  const _Float16* ka[4]; const _Float16* va[4];
  int kl[4], vl[4];
#pragma unroll
  for (int i = 0; i < 4; ++i) {
    int c = i * 256 + tid;
    int row = c >> 4, cc = c & 15, gk = cc ^ (row & 15);
    ka[i] = Kp + (size_t)row * 2048 + gk * 8;   // + t*64*2048 per tile
    kl[i] = c * 8;
    int rv = c >> 3, cv = c & 7, gv = cv ^ (rv & 7);
    va[i] = Vp + (size_t)rv * 2048 + gv * 8;    // + t*64 per tile
    vl[i] = c * 8;
  }

  // Prologue: stage tile 0 into buf0.
#pragma unroll
  for (int i = 0; i < 4; ++i) async16(ka[i], &Ks[0][kl[i]]);
#pragma unroll
  for (int i = 0; i < 4; ++i) async16(va[i], &Vs[0][vl[i]]);

  half8 qf[2][4];
#pragma unroll
  for (int qt = 0; qt < 2; ++qt)
#pragma unroll
    for (int ks = 0; ks < 4; ++ks)
      qf[qt][ks] = *reinterpret_cast<const half8*>(
          Qp + (size_t)(qt * 16 + l15) * 2048 + ks * 32 + l4 * 8);

  VMW(0);          // tile-0 staged (Q loads also drained; counting stays simple)
  SBAR();

  floatx4 oacc[2][8] = {};
  float lsumq[2] = {0.f, 0.f};        // per-lane: sum over its s for q = lane&15

  for (int t = 0; t < 32; ++t) {
    const int c = t & 1, nx = c ^ 1;
    if (t < 31) {                     // issue t+1 loads; land during compute(t)
      const size_t kofs = (size_t)(t * 64 + 64);
#pragma unroll
      for (int i = 0; i < 4; ++i) async16(ka[i] + kofs * 2048, &Ks[nx][kl[i]]);
#pragma unroll
      for (int i = 0; i < 4; ++i) async16(va[i] + kofs, &Vs[nx][vl[i]]);
    }

    // ---- S^T = K Q^T : sacc[st][qt], col=q, row=s ----
    floatx4 sacc[4][2] = {};
#pragma unroll
    for (int ks = 0; ks < 4; ++ks) {
      half8 kf[4];
#pragma unroll
      for (int st = 0; st < 4; ++st) {
        int row = st * 16 + l15;
        int ch = (ks * 4 + l4) ^ l15;             // row & 15 == l15
        kf[st] = *reinterpret_cast<const half8*>(&Ks[c][row * 128 + ch * 8]);
      }
#pragma unroll
      for (int st = 0; st < 4; ++st)
#pragma unroll
        for (int qt = 0; qt < 2; ++qt)
          sacc[st][qt] = __builtin_amdgcn_mfma_f32_16x16x32_f16(kf[st], qf[qt][ks], sacc[st][qt], 0, 0, 0);
    }

    // ---- p = 2^s; packed b64 Ps write (4 consecutive s per lane) ----
#pragma unroll
    for (int qt = 0; qt < 2; ++qt)
#pragma unroll
      for (int st = 0; st < 4; ++st) {
        float p0 = exp2f(sacc[st][qt][0]);
        float p1 = exp2f(sacc[st][qt][1]);
        float p2 = exp2f(sacc[st][qt][2]);
        float p3 = exp2f(sacc[st][qt][3]);
        lsumq[qt] += (p0 + p1) + (p2 + p3);
        half4 pv;
        pv[0] = (_Float16)p0; pv[1] = (_Float16)p1;
        pv[2] = (_Float16)p2; pv[3] = (_Float16)p3;
        int ch = (st * 2 + (l4 >> 1)) ^ (l15 & 7);
        *reinterpret_cast<half4*>(
            &Ps[(wave * 32 + qt * 16 + l15) * 64 + ch * 8 + (l4 & 1) * 4]) = pv;
      }

    __builtin_amdgcn_s_waitcnt(0xC07F);  // lgkmcnt(0): own-wave ds_write->ds_read

    // ---- O += P V  (V stored (d,s): NT GEMM) ----
#pragma unroll
    for (int ks2 = 0; ks2 < 2; ++ks2) {
      half8 pf[2];
#pragma unroll
      for (int mt = 0; mt < 2; ++mt)
        pf[mt] = *reinterpret_cast<const half8*>(
            &Ps[(wave * 32 + mt * 16 + l15) * 64 + (((ks2 * 4 + l4) ^ (l15 & 7)) * 8)]);
#pragma unroll
      for (int nt2 = 0; nt2 < 8; ++nt2) {
        int row = nt2 * 16 + l15;
        int ch = (ks2 * 4 + l4) ^ (row & 7);
        half8 vf = *reinterpret_cast<const half8*>(&Vs[c][row * 64 + ch * 8]);
#pragma unroll
        for (int mt = 0; mt < 2; ++mt)
          oacc[mt][nt2] = __builtin_amdgcn_mfma_f32_16x16x32_f16(pf[mt], vf, oacc[mt][nt2], 0, 0, 0);
      }
    }

    // t+1's loads had all of compute(t) to fly; barrier ends reads of buf[c].
    if (t < 31) VMW(0);
    SBAR();
  }

#pragma unroll
  for (int qt = 0; qt < 2; ++qt) {
    lsumq[qt] += __shfl_xor(lsumq[qt], 16);
    lsumq[qt] += __shfl_xor(lsumq[qt], 32);
  }

  _Float16* Op = O + ((size_t)(b * 2048 + q0 + wave * 32)) * 2048 + h * 128;
#pragma unroll
  for (int mt = 0; mt < 2; ++mt)
#pragma unroll
    for (int r = 0; r < 4; ++r) {
      float inv = 1.0f / __shfl(lsumq[mt], l4 * 4 + r);
#pragma unroll
      for (int nt2 = 0; nt2 < 8; ++nt2) {
        int row = mt * 16 + l4 * 4 + r;
        int col = nt2 * 16 + l15;
        Op[(size_t)row * 2048 + col] = (_Float16)(oacc[mt][nt2][r] * inv);
      }
    }
}

// ---------------------------------------------------------------------------
extern "C" void kernel_launch(void* const* d_in, const int* in_sizes, int n_in,
                              void* d_out, int out_size, void* d_ws, size_t ws_size,
                              hipStream_t stream) {
  const float* x = (const float*)d_in[0];
  const float* wq = (const float*)d_in[1];
  const float* wk = (const float*)d_in[2];
  const float* wv = (const float*)d_in[3];
  const float* wo = (const float*)d_in[4];
  float* out = (float*)d_out;

  const size_t XN = (size_t)4096 * 2048;
  const size_t WN = (size_t)2048 * 2048;
  _Float16* xh = (_Float16*)d_ws;
  _Float16* qh = xh + XN;          // Q then K contiguous (row-major, ld 2048)
  _Float16* vth = xh + 3 * XN;     // per-batch transposed V
  _Float16* oh = xh + 4 * XN;
  _Float16* wqh = xh + 5 * XN;     // wq,wk,wv,wo contiguous

  const float SM_SCALE = 0.08838834764831845f * 1.4426950408889634f;

  cvt_all<<<dim3(24576), 256, 0, stream>>>(x, wq, wk, wv, wo, xh, wqh, SM_SCALE);
  gemm_nt<<<dim3(384), 512, 0, stream>>>(xh, wqh, qh, vth);
  flash_attn<<<dim3(16, 32), 256, 0, stream>>>(qh, qh + XN, vth, oh);
  gemm_wo<<<dim3(16, 32), 256, 0, stream>>>(oh, wqh + 3 * WN, out);
}